// Round 4
// baseline (191.692 us; speedup 1.0000x reference)
//
#include <hip/hip_runtime.h>
#include <cstdint>
#include <cstddef>

#define SEQ   2048
#define HID   2048
#define NHEAD 16
#define HDIM  128
#define NQKV  2560
#define KOFF  2048
#define VOFF  2304
#define SCALE 0.08838834764831845f

typedef __bf16 bf16_t;
typedef __attribute__((ext_vector_type(8))) __bf16 bf16x8;
typedef __attribute__((ext_vector_type(4))) float f32x4;

static __device__ __forceinline__ void gl_lds16(const void* g, void* l) {
  __builtin_amdgcn_global_load_lds((const __attribute__((address_space(1))) void*)g,
                                   (__attribute__((address_space(3))) void*)l, 16, 0, 0);
}

// ---------- fp32 -> bf16 convert (x), 8 elems/thread ----------
__global__ void k_cvt(const float* __restrict__ in, bf16_t* __restrict__ outp) {
  int i = blockIdx.x * blockDim.x + threadIdx.x;
  const float4* p = (const float4*)in;
  float4 a = p[2 * i], b = p[2 * i + 1];
  bf16x8 o;
  o[0] = (bf16_t)a.x; o[1] = (bf16_t)a.y; o[2] = (bf16_t)a.z; o[3] = (bf16_t)a.w;
  o[4] = (bf16_t)b.x; o[5] = (bf16_t)b.y; o[6] = (bf16_t)b.z; o[7] = (bf16_t)b.w;
  ((bf16x8*)outp)[i] = o;
}

// ---------- concat bias (fp32) ----------
__global__ void k_bias(const float* __restrict__ bq, const float* __restrict__ bk,
                       const float* __restrict__ bv, float* __restrict__ bias) {
  int i = blockIdx.x * blockDim.x + threadIdx.x;
  if (i < NQKV) bias[i] = (i < KOFF) ? bq[i] : ((i < VOFF) ? bk[i - KOFF] : bv[i - VOFF]);
}

// ---------- transpose + convert weight: in fp32 [K][N] -> out bf16 [N][K] ----------
__global__ void k_twt(const float* __restrict__ in, bf16_t* __restrict__ outp, int K, int N) {
  __shared__ float t[32][33];
  int x = threadIdx.x, y = threadIdx.y;
  int c0 = blockIdx.x * 32, r0 = blockIdx.y * 32;
#pragma unroll
  for (int j = 0; j < 32; j += 8) t[y + j][x] = in[(size_t)(r0 + y + j) * N + c0 + x];
  __syncthreads();
#pragma unroll
  for (int j = 0; j < 32; j += 8)
    outp[(size_t)(c0 + y + j) * K + r0 + x] = (bf16_t)t[x][y + j];
}

// ---------- bf16 transpose V -> Vg[d][sigma], sigma interleaved within 32-runs:
// sigma(s) = (s&~31) | ((s&15)<<1) | ((s>>4)&1)
__global__ void k_tv(const bf16_t* __restrict__ QKV, bf16_t* __restrict__ Vg) {
  __shared__ bf16_t t[32][33];
  int x = threadIdx.x, y = threadIdx.y;
  int s0 = blockIdx.x * 32, d0 = blockIdx.y * 32;
#pragma unroll
  for (int j = 0; j < 32; j += 8)
    t[y + j][x] = QKV[(size_t)(s0 + y + j) * NQKV + VOFF + d0 + x];
  __syncthreads();
  int sig = ((x & 15) << 1) | (x >> 4);
#pragma unroll
  for (int j = 0; j < 32; j += 8)
    Vg[(size_t)(d0 + y + j) * SEQ + s0 + sig] = t[x][y + j];
}

// ---------- pipelined GEMM: C[M,N] = A[M,K] @ Bt[N,K]^T (+bias) ----------
// 128x128 tile, BK=32, 4 waves, triple-buffered LDS, 2-deep prefetch with
// counted vmcnt + raw s_barrier (no full drains in steady state).
// LDS swizzle: 4 slots/row, ss = sp ^ ((row>>3)&3) -> 2 lanes/16B-position (free).
template <int BIAS, typename OUTT>
__global__ __launch_bounds__(256) void k_gemm(const bf16_t* __restrict__ A,
                                              const bf16_t* __restrict__ Bt,
                                              const float* __restrict__ bias,
                                              OUTT* __restrict__ C,
                                              int M, int N, int K) {
  __shared__ __align__(16) bf16_t As[3][128 * 32];
  __shared__ __align__(16) bf16_t Bs[3][128 * 32];
  const int tid = threadIdx.x;
  const int l = tid & 63, w = tid >> 6;
  const int lr = l & 15, lg = l >> 4;
  const int m0 = blockIdx.y * 128, n0 = blockIdx.x * 128;
  const int wm = (w >> 1) * 64, wn = (w & 1) * 64;
  const int NT = K >> 5;
  f32x4 acc[4][4] = {};

#define GSTAGE(buf, ktv)                                                          \
  {                                                                               \
    _Pragma("unroll") for (int t = 0; t < 2; ++t) {                               \
      int c = t * 256 + tid;                                                      \
      int r = c >> 2, ss = (c & 3) ^ ((r >> 3) & 3);                              \
      gl_lds16(A + (size_t)(m0 + r) * K + (ktv) + ss * 8,                         \
               &As[buf][(size_t)(t * 256 + w * 64) * 8]);                         \
    }                                                                             \
    _Pragma("unroll") for (int t = 0; t < 2; ++t) {                               \
      int c = t * 256 + tid;                                                      \
      int r = c >> 2, ss = (c & 3) ^ ((r >> 3) & 3);                              \
      gl_lds16(Bt + (size_t)(n0 + r) * K + (ktv) + ss * 8,                        \
               &Bs[buf][(size_t)(t * 256 + w * 64) * 8]);                         \
    }                                                                             \
  }

  GSTAGE(0, 0);
  GSTAGE(1, 32);
  int bufc = 0;
  for (int i = 0; i < NT; ++i) {
    if (i + 2 < NT) {
      int bn = bufc + 2; if (bn >= 3) bn -= 3;
      GSTAGE(bn, (i + 2) * 32);
      asm volatile("s_waitcnt vmcnt(8)" ::: "memory");
    } else if (i + 2 == NT) {
      asm volatile("s_waitcnt vmcnt(4)" ::: "memory");
    } else {
      asm volatile("s_waitcnt vmcnt(0)" ::: "memory");
    }
    asm volatile("s_barrier" ::: "memory");
    bf16x8 af[4], bfr[4];
#pragma unroll
    for (int i4 = 0; i4 < 4; ++i4) {
      int ra = wm + i4 * 16 + lr;
      af[i4] = *(const bf16x8*)&As[bufc][ra * 32 + (lg ^ ((ra >> 3) & 3)) * 8];
    }
#pragma unroll
    for (int i4 = 0; i4 < 4; ++i4) {
      int rb = wn + i4 * 16 + lr;
      bfr[i4] = *(const bf16x8*)&Bs[bufc][rb * 32 + (lg ^ ((rb >> 3) & 3)) * 8];
    }
#pragma unroll
    for (int mi = 0; mi < 4; ++mi)
#pragma unroll
      for (int ni = 0; ni < 4; ++ni)
        acc[mi][ni] =
            __builtin_amdgcn_mfma_f32_16x16x32_bf16(af[mi], bfr[ni], acc[mi][ni], 0, 0, 0);
    asm volatile("s_barrier" ::: "memory");
    bufc = (bufc + 1 == 3) ? 0 : bufc + 1;
  }
#undef GSTAGE

#pragma unroll
  for (int mi = 0; mi < 4; ++mi)
#pragma unroll
    for (int ni = 0; ni < 4; ++ni) {
      int col = n0 + wn + ni * 16 + lr;
      float bb = BIAS ? bias[col] : 0.0f;
#pragma unroll
      for (int r = 0; r < 4; ++r) {
        int row = m0 + wm + mi * 16 + lg * 4 + r;
        float v = acc[mi][ni][r] + bb;
        if constexpr (sizeof(OUTT) == 2)
          C[(size_t)row * N + col] = (OUTT)v;
        else
          C[(size_t)row * N + col] = v;
      }
    }
}

// ---------- flash attention, causal, GQA — swapped-QK^T, 32 q-rows/wave ----------
// grid (16 heads, 32 qblocks); block 128 = 2 waves, each wave 32 q rows (2 halves of 16).
// K/V LDS fragments are read ONCE and reused for both q-halves -> LDS reads per MFMA halved.
// Layouts identical to R3 (verified): K[64][128] slot^=(row&15); V sigma-interleaved rows,
// staged via global_load_lds with pre-swizzled global source, double-buffered.
__global__ __launch_bounds__(128) void k_attn(const bf16_t* __restrict__ QKV,
                                              const bf16_t* __restrict__ Vg,
                                              bf16_t* __restrict__ AO) {
  __shared__ __align__(16) bf16_t Kl[2 * 64 * 128];
  __shared__ __align__(16) bf16_t Vl[2 * 64 * 128];
  const int h = blockIdx.x;
  const int y = blockIdx.y;
  const int qb = (y < 16) ? (31 - y) : (y - 16);  // heavy+light pairing (sum=33)
  const int hkv = h >> 3;
  const int tid = threadIdx.x;
  const int l = tid & 63, w = tid >> 6;
  const int lr = l & 15, lg = l >> 4;
  const int q0 = qb * 64 + w * 32;

  // Q fragments for both 16-row halves (B-operand: col=lane&15=q, k-slot=(lane>>4)*8)
  bf16x8 qf[2][4];
#pragma unroll
  for (int qh = 0; qh < 2; ++qh)
#pragma unroll
    for (int dt = 0; dt < 4; ++dt)
      qf[qh][dt] =
          *(const bf16x8*)(QKV + (size_t)(q0 + qh * 16 + lr) * NQKV + h * HDIM + dt * 32 + lg * 8);

  f32x4 oa[2][8] = {};
  float mm[2] = {-1e30f, -1e30f}, ls[2] = {0.0f, 0.0f};

  // staging bases: chunk c = t*128+tid (t=0..7): r = 8t + r0, ss = ss0 ^ (8*(t&1))
  const int r0 = tid >> 4, sp = tid & 15;
  const int ss0 = sp ^ r0, b0v = ss0 >> 3;
  const bf16_t* baseKe = QKV + (size_t)r0 * NQKV + KOFF + hkv * HDIM + ss0 * 8;
  const bf16_t* baseKo = QKV + (size_t)r0 * NQKV + KOFF + hkv * HDIM + (ss0 ^ 8) * 8;
  const bf16_t* baseVe = Vg + (size_t)(hkv * HDIM + 2 * r0 + b0v) * SEQ + (ss0 & 7) * 8;
  const bf16_t* baseVo = Vg + (size_t)(hkv * HDIM + 2 * r0 + (b0v ^ 1)) * SEQ + (ss0 & 7) * 8;

#define STAGE(b, kbv)                                                              \
  {                                                                                \
    bf16_t* Kb = Kl + (b) * 8192;                                                  \
    bf16_t* Vb = Vl + (b) * 8192;                                                  \
    size_t kO = (size_t)(kbv) * 64 * NQKV;                                         \
    int vO = (kbv) * 64;                                                           \
    _Pragma("unroll") for (int t = 0; t < 8; ++t) {                                \
      const bf16_t* s = ((t & 1) ? baseKo : baseKe) + kO + (size_t)(8 * t) * NQKV; \
      gl_lds16(s, Kb + (size_t)(t * 128 + w * 64) * 8);                            \
    }                                                                              \
    _Pragma("unroll") for (int t = 0; t < 8; ++t) {                                \
      const bf16_t* s = ((t & 1) ? baseVo : baseVe) + vO + (size_t)(16 * t) * SEQ; \
      gl_lds16(s, Vb + (size_t)(t * 128 + w * 64) * 8);                            \
    }                                                                              \
  }

  STAGE(0, 0);
  asm volatile("s_waitcnt vmcnt(0)" ::: "memory");
  __syncthreads();
  int cur = 0;

  for (int kb = 0; kb <= qb; ++kb) {
    if (kb < qb) STAGE(cur ^ 1, kb + 1);
    const bf16_t* Kb = Kl + cur * 8192;
    const bf16_t* Vb = Vl + cur * 8192;

    bf16x8 pf[2][2];
    float al[2];
#pragma unroll
    for (int qh = 0; qh < 2; ++qh) {
      // S^T = K @ Q^T : lane holds S[k=ki*16+lg*4+r][q=q0+qh*16+lr]
      float sc[4][4];
#pragma unroll
      for (int ki = 0; ki < 4; ++ki) {
        f32x4 sa = {};
        int krow = ki * 16 + lr;
#pragma unroll
        for (int dt = 0; dt < 4; ++dt) {
          bf16x8 kf = *(const bf16x8*)(Kb + krow * 128 + (((dt * 4 + lg) ^ lr) * 8));
          sa = __builtin_amdgcn_mfma_f32_16x16x32_bf16(kf, qf[qh][dt], sa, 0, 0, 0);
        }
#pragma unroll
        for (int r = 0; r < 4; ++r) {
          float s = sa[r] * SCALE;
          if (kb == qb) {
            int kg = kb * 64 + ki * 16 + lg * 4 + r;
            if (kg > q0 + qh * 16 + lr) s = -1e30f;
          }
          sc[ki][r] = s;
        }
      }

      // online softmax for q-row (in-lane 16 + 2 shfl across lg groups)
      float t0 = fmaxf(fmaxf(sc[0][0], sc[0][1]), fmaxf(sc[0][2], sc[0][3]));
      float t1 = fmaxf(fmaxf(sc[1][0], sc[1][1]), fmaxf(sc[1][2], sc[1][3]));
      float t2 = fmaxf(fmaxf(sc[2][0], sc[2][1]), fmaxf(sc[2][2], sc[2][3]));
      float t3 = fmaxf(fmaxf(sc[3][0], sc[3][1]), fmaxf(sc[3][2], sc[3][3]));
      float tm = fmaxf(fmaxf(t0, t1), fmaxf(t2, t3));
      tm = fmaxf(tm, __shfl_xor(tm, 16));
      tm = fmaxf(tm, __shfl_xor(tm, 32));
      float mn = fmaxf(mm[qh], tm);
      al[qh] = __expf(mm[qh] - mn);
      mm[qh] = mn;
      float rs = 0.0f;
#pragma unroll
      for (int ki = 0; ki < 4; ++ki) {
        float p0 = __expf(sc[ki][0] - mn), p1 = __expf(sc[ki][1] - mn);
        float p2 = __expf(sc[ki][2] - mn), p3 = __expf(sc[ki][3] - mn);
        sc[ki][0] = p0; sc[ki][1] = p1; sc[ki][2] = p2; sc[ki][3] = p3;
        rs += (p0 + p1) + (p2 + p3);
      }
      rs += __shfl_xor(rs, 16);
      rs += __shfl_xor(rs, 32);
      ls[qh] = ls[qh] * al[qh] + rs;

      // pack P into A-fragments: pf[qh][kp][e] = sc[2kp+(e&1)][e>>1]
#pragma unroll
      for (int kp = 0; kp < 2; ++kp) {
        pf[qh][kp][0] = (bf16_t)sc[2 * kp][0]; pf[qh][kp][1] = (bf16_t)sc[2 * kp + 1][0];
        pf[qh][kp][2] = (bf16_t)sc[2 * kp][1]; pf[qh][kp][3] = (bf16_t)sc[2 * kp + 1][1];
        pf[qh][kp][4] = (bf16_t)sc[2 * kp][2]; pf[qh][kp][5] = (bf16_t)sc[2 * kp + 1][2];
        pf[qh][kp][6] = (bf16_t)sc[2 * kp][3]; pf[qh][kp][7] = (bf16_t)sc[2 * kp + 1][3];
      }
    }

    // rescale O accumulators (O[qh] row q=lg*4+r, col d=lr)
#pragma unroll
    for (int qh = 0; qh < 2; ++qh) {
      float a0 = __shfl(al[qh], lg * 4 + 0);
      float a1 = __shfl(al[qh], lg * 4 + 1);
      float a2 = __shfl(al[qh], lg * 4 + 2);
      float a3 = __shfl(al[qh], lg * 4 + 3);
#pragma unroll
      for (int dt = 0; dt < 8; ++dt) {
        oa[qh][dt][0] *= a0; oa[qh][dt][1] *= a1;
        oa[qh][dt][2] *= a2; oa[qh][dt][3] *= a3;
      }
    }

    // O += P @ V : V fragments read once, shared across both q-halves
#pragma unroll
    for (int kp = 0; kp < 2; ++kp)
#pragma unroll
      for (int dt = 0; dt < 8; ++dt) {
        int R = dt * 8 + (lr >> 1);
        int slot = (((lr & 1) * 8 + kp * 4 + lg) ^ (R & 15));
        bf16x8 vf = *(const bf16x8*)(Vb + R * 128 + slot * 8);
        oa[0][dt] = __builtin_amdgcn_mfma_f32_16x16x32_bf16(pf[0][kp], vf, oa[0][dt], 0, 0, 0);
        oa[1][dt] = __builtin_amdgcn_mfma_f32_16x16x32_bf16(pf[1][kp], vf, oa[1][dt], 0, 0, 0);
      }

    asm volatile("s_waitcnt vmcnt(0)" ::: "memory");
    __syncthreads();
    cur ^= 1;
  }
#undef STAGE

  // epilogue: normalize and store
#pragma unroll
  for (int qh = 0; qh < 2; ++qh) {
    float l0 = __shfl(ls[qh], lg * 4 + 0);
    float l1 = __shfl(ls[qh], lg * 4 + 1);
    float l2 = __shfl(ls[qh], lg * 4 + 2);
    float l3 = __shfl(ls[qh], lg * 4 + 3);
    float i0 = 1.0f / l0, i1 = 1.0f / l1, i2 = 1.0f / l2, i3 = 1.0f / l3;
#pragma unroll
    for (int dt = 0; dt < 8; ++dt) {
      int d = h * HDIM + dt * 16 + lr;
      size_t rowb = (size_t)(q0 + qh * 16 + lg * 4);
      AO[(rowb + 0) * HID + d] = (bf16_t)(oa[qh][dt][0] * i0);
      AO[(rowb + 1) * HID + d] = (bf16_t)(oa[qh][dt][1] * i1);
      AO[(rowb + 2) * HID + d] = (bf16_t)(oa[qh][dt][2] * i2);
      AO[(rowb + 3) * HID + d] = (bf16_t)(oa[qh][dt][3] * i3);
    }
  }
}

extern "C" void kernel_launch(void* const* d_in, const int* in_sizes, int n_in,
                              void* d_out, int out_size, void* d_ws, size_t ws_size,
                              hipStream_t stream) {
  (void)in_sizes; (void)n_in; (void)out_size; (void)ws_size;
  const float* x  = (const float*)d_in[0];
  const float* Wq = (const float*)d_in[1];
  const float* bq = (const float*)d_in[2];
  const float* Wk = (const float*)d_in[3];
  const float* bk = (const float*)d_in[4];
  const float* Wv = (const float*)d_in[5];
  const float* bv = (const float*)d_in[6];
  const float* Wo = (const float*)d_in[7];
  float* outp = (float*)d_out;

  char* ws = (char*)d_ws;
  const size_t OFF_XB   = 0;                      // [2048][2048] bf16
  const size_t OFF_WQKV = 8388608;                // [2560][2048] bf16 (Wq^T;Wk^T;Wv^T)
  const size_t OFF_WOT  = OFF_WQKV + 10485760;    // [2048][2048] bf16
  const size_t OFF_QKV  = OFF_WOT + 8388608;      // [2048][2560] bf16
  const size_t OFF_VT   = OFF_QKV + 10485760;     // [256][2048] bf16 (sigma-interleaved)
  const size_t OFF_AO   = OFF_VT + 1048576;       // [2048][2048] bf16
  const size_t OFF_BIAS = OFF_AO + 8388608;       // [2560] fp32
  bf16_t* xb    = (bf16_t*)(ws + OFF_XB);
  bf16_t* WqkvT = (bf16_t*)(ws + OFF_WQKV);
  bf16_t* WoT   = (bf16_t*)(ws + OFF_WOT);
  bf16_t* QKV   = (bf16_t*)(ws + OFF_QKV);
  bf16_t* Vg    = (bf16_t*)(ws + OFF_VT);
  bf16_t* AO    = (bf16_t*)(ws + OFF_AO);
  float*  bias  = (float*)(ws + OFF_BIAS);

  k_cvt<<<2048, 256, 0, stream>>>(x, xb);
  k_bias<<<10, 256, 0, stream>>>(bq, bk, bv, bias);
  k_twt<<<dim3(64, 64), dim3(32, 8), 0, stream>>>(Wq, WqkvT, 2048, 2048);
  k_twt<<<dim3(8, 64), dim3(32, 8), 0, stream>>>(Wk, WqkvT + (size_t)2048 * 2048, 2048, 256);
  k_twt<<<dim3(8, 64), dim3(32, 8), 0, stream>>>(Wv, WqkvT + (size_t)2304 * 2048, 2048, 256);
  k_twt<<<dim3(64, 64), dim3(32, 8), 0, stream>>>(Wo, WoT, 2048, 2048);
  k_gemm<1, bf16_t><<<dim3(20, 16), 256, 0, stream>>>(xb, WqkvT, bias, QKV, 2048, 2560, 2048);
  k_tv<<<dim3(64, 8), dim3(32, 8), 0, stream>>>(QKV, Vg);
  k_attn<<<dim3(16, 32), 128, 0, stream>>>(QKV, Vg, AO);
  k_gemm<0, float><<<dim3(16, 16), 256, 0, stream>>>(AO, WoT, nullptr, outp, 2048, 2048, 2048);
}